// Round 20
// baseline (52.204 us; speedup 1.0000x reference)
//
#include <hip/hip_runtime.h>
#include <hip/hip_bf16.h>

typedef __attribute__((ext_vector_type(2)))  float f32x2;
typedef __attribute__((ext_vector_type(4)))  float f32x4;
typedef __attribute__((ext_vector_type(8)))  float f32x8;
typedef __attribute__((ext_vector_type(2)))  __bf16 bf16x2;
typedef __attribute__((ext_vector_type(8)))  __bf16 bf16x8;
typedef __attribute__((ext_vector_type(4)))  unsigned int u32x4;

static __device__ __forceinline__ bf16x8 cvt8(f32x8 v) {
    return __builtin_convertvector(v, bf16x8);
}
static __device__ __forceinline__ unsigned int pkcvt(f32x2 v) {
    return __builtin_bit_cast(unsigned int, __builtin_convertvector(v, bf16x2));
}
static __device__ __forceinline__ f32x2 max2(f32x2 v) {
    const f32x2 z = {0.f, 0.f};
    return __builtin_elementwise_max(v, z);
}

#define MFMA16(A, B, C) __builtin_amdgcn_mfma_f32_16x16x32_bf16((A), (B), (C), 0, 0, 0)

// Native 16x16x32 bf16 chain — f32x4 accumulators (4 regs, no AGPR banking).
// Layouts (16x16x32): A/B lane l: row/col = l&15, k = 8*(l>>4) + elem.
//                     C/D lane l: col = l&15, row = 4*(l>>4) + reg.
// HID=16 < K=32: lane-group g's 4 D-rows (4g+r) are packed into B elems 0..3
// with A's k-columns 8g+4..8g+7 ZEROED — half-empty MFMA, same 1-inst cost,
// zero cross-lane ops.
//   L1: D1[hid][p] = W1^T x^T + b1 (b1 via k=2; B k-slot 2 = 1.0; no masking
//       needed: A1's k>=3 columns are zero so B garbage contributes 0).
//   L2: D2[j][p] = W2'^T relu(D1) + b2 (A2 k-packed per above; C = b2).
//   L3: row-selective A3 (row e = w3_e, k-packed), chained C seeded with b3
//       -> lanes 0..15 end with (y0,y1,y2) in regs 0..2.
__global__ __launch_bounds__(256, 4) void mlp3_mfma16(
    const float* __restrict__ x,
    const float* __restrict__ W1, const float* __restrict__ b1,
    const float* __restrict__ W2, const float* __restrict__ b2,
    const float* __restrict__ W3, const float* __restrict__ b3,
    float* __restrict__ out, int n)
{
    const int tid  = (int)threadIdx.x;
    const int lane = tid & 63;
    const int col  = lane & 15;   // A row / B col / D col
    const int g    = lane >> 4;   // k-group: B k = 8g+e; D rows 4g+r
    const int wv   = tid >> 6;

    // ---- weight fragments / constants (resident; small) ----
    bf16x8 a1[3], a2[3], a3[3];
    f32x4  c2[3];
    #pragma unroll
    for (int e = 0; e < 3; ++e) {
        f32x8 t = {0.f,0.f,0.f,0.f,0.f,0.f,0.f,0.f};
        if (g == 0) {                        // k=0,1,2 live in group 0
            t[0] = W1[e * 32 + col];         // W1[e][0][col]
            t[1] = W1[e * 32 + 16 + col];    // W1[e][1][col]
            t[2] = b1[e * 16 + col];         // b1 (x k-slot 2 = 1.0)
        }
        a1[e] = cvt8(t);
        f32x8 t2 = {0.f,0.f,0.f,0.f,0.f,0.f,0.f,0.f};
        #pragma unroll
        for (int i = 0; i < 4; ++i)          // k-slot 8g+i <- W2[4g+i][col]
            t2[i] = W2[e * 256 + (4 * g + i) * 16 + col];
        a2[e] = cvt8(t2);                     // slots 4..7 zero
        f32x8 t3 = {0.f,0.f,0.f,0.f,0.f,0.f,0.f,0.f};
        if (col == e) {
            #pragma unroll
            for (int i = 0; i < 4; ++i)
                t3[i] = W3[e * 16 + 4 * g + i];
        }
        a3[e] = cvt8(t3);
        #pragma unroll
        for (int r = 0; r < 4; ++r)
            c2[e][r] = b2[e * 16 + 4 * g + r];
    }
    f32x4 c30 = {0.f, 0.f, 0.f, 0.f};        // C3 seed: group0 regs 0..2 = b3
    if (g == 0) { c30[0] = b3[0]; c30[1] = b3[1]; c30[2] = b3[2]; }
    const f32x4 zz = {0.f, 0.f, 0.f, 0.f};

    const int xoff = (wv * 32 + col) * 8;    // bytes into 1024B x-chunk; tile1 +128
    const int ooff = (wv * 32 + col) * 12;   // bytes into 1536B out-chunk; tile1 +192

    const int nblk   = n >> 7;               // 128 points per block-iter
    const int stride = (int)gridDim.x;
    const size_t xstep = (size_t)stride * 1024;
    const size_t ostep = (size_t)stride * 1536;

    int cb = (int)blockIdx.x;
    const char* xp = (const char*)x + (size_t)cb * 1024 + xoff;
    char*       op = (char*)out + (size_t)cb * 1536 + ooff;

    float2 xv0 = *reinterpret_cast<const float2*>(xp);
    float2 xv1 = *reinterpret_cast<const float2*>(xp + 128);

    f32x4 y0, y1;
    char* paddr = nullptr;
    bool  pendv = false;

    while (true) {
        const bool more = (cb + stride) < nblk;
        float2 xn0, xn1;
        if (more) {                           // prefetch next iter's x
            xn0 = *reinterpret_cast<const float2*>(xp + xstep);
            xn1 = *reinterpret_cast<const float2*>(xp + xstep + 128);
        }

        // previous iteration's stores issued here (drain deadline 18 MFMAs away)
        if (pendv && lane < 16) {
            *reinterpret_cast<float3*>(paddr)       = make_float3(y0[0], y0[1], y0[2]);
            *reinterpret_cast<float3*>(paddr + 192) = make_float3(y1[0], y1[1], y1[2]);
        }

        // B1: k-slots {x0, x1, 1.0, 0...} in every group (A1 zero outside g0)
        u32x4 bu0 = { pkcvt((f32x2){xv0.x, xv0.y}), 0x3F80u, 0u, 0u };
        u32x4 bu1 = { pkcvt((f32x2){xv1.x, xv1.y}), 0x3F80u, 0u, 0u };
        const bf16x8 bx0 = __builtin_bit_cast(bf16x8, bu0);
        const bf16x8 bx1 = __builtin_bit_cast(bf16x8, bu1);

        #pragma unroll
        for (int e = 0; e < 3; ++e) {
            f32x4 t10 = MFMA16(a1[e], bx0, zz);
            f32x4 t11 = MFMA16(a1[e], bx1, zz);
            u32x4 w0 = { pkcvt(max2((f32x2){t10[0], t10[1]})),
                         pkcvt(max2((f32x2){t10[2], t10[3]})), 0u, 0u };
            u32x4 w1 = { pkcvt(max2((f32x2){t11[0], t11[1]})),
                         pkcvt(max2((f32x2){t11[2], t11[3]})), 0u, 0u };
            f32x4 t20 = MFMA16(a2[e], __builtin_bit_cast(bf16x8, w0), c2[e]);
            f32x4 t21 = MFMA16(a2[e], __builtin_bit_cast(bf16x8, w1), c2[e]);
            u32x4 v0 = { pkcvt(max2((f32x2){t20[0], t20[1]})),
                         pkcvt(max2((f32x2){t20[2], t20[3]})), 0u, 0u };
            u32x4 v1 = { pkcvt(max2((f32x2){t21[0], t21[1]})),
                         pkcvt(max2((f32x2){t21[2], t21[3]})), 0u, 0u };
            y0 = MFMA16(a3[e], __builtin_bit_cast(bf16x8, v0), (e == 0) ? c30 : y0);
            y1 = MFMA16(a3[e], __builtin_bit_cast(bf16x8, v1), (e == 0) ? c30 : y1);
        }

        paddr = op;
        pendv = true;

        if (!more) break;
        cb += stride;
        xp += xstep;
        op += ostep;
        xv0 = xn0; xv1 = xn1;
    }

    if (pendv && lane < 16) {
        *reinterpret_cast<float3*>(paddr)       = make_float3(y0[0], y0[1], y0[2]);
        *reinterpret_cast<float3*>(paddr + 192) = make_float3(y1[0], y1[1], y1[2]);
    }
}

extern "C" void kernel_launch(void* const* d_in, const int* in_sizes, int n_in,
                              void* d_out, int out_size, void* d_ws, size_t ws_size,
                              hipStream_t stream) {
    const float* x  = (const float*)d_in[0];
    const float* W1 = (const float*)d_in[1];
    const float* b1 = (const float*)d_in[2];
    const float* W2 = (const float*)d_in[3];
    const float* b2 = (const float*)d_in[4];
    const float* W3 = (const float*)d_in[5];
    const float* b3 = (const float*)d_in[6];
    float* out = (float*)d_out;
    (void)d_ws; (void)ws_size; (void)n_in; (void)out_size;

    const int n = in_sizes[0] / 2;   // 4194304 points (32768 * 128)
    const int block = 256;
    const int grid = 2048;           // persistent: 16 chunk-iterations per block

    mlp3_mfma16<<<grid, block, 0, stream>>>(x, W1, b1, W2, b2, W3, b3, out, n);
}

// Round 21
// 46.767 us; speedup vs baseline: 1.1162x; 1.1162x over previous
//
#include <hip/hip_runtime.h>
#include <hip/hip_bf16.h>

typedef __attribute__((ext_vector_type(2)))  float f32x2;
typedef __attribute__((ext_vector_type(8)))  float f32x8;
typedef __attribute__((ext_vector_type(16))) float f32x16;
typedef __attribute__((ext_vector_type(2)))  __bf16 bf16x2;
typedef __attribute__((ext_vector_type(8)))  __bf16 bf16x8;
typedef __attribute__((ext_vector_type(4)))  unsigned int u32x4;

static __device__ __forceinline__ bf16x8 cvt8(f32x8 v) {
    return __builtin_convertvector(v, bf16x8);
}
static __device__ __forceinline__ unsigned int pkcvt(f32x2 v) {
    return __builtin_bit_cast(unsigned int, __builtin_convertvector(v, bf16x2));
}
static __device__ __forceinline__ f32x2 max2(f32x2 v) {
    const f32x2 z = {0.f, 0.f};
    return __builtin_elementwise_max(v, z);
}

#define MFMA32(A, B, C) __builtin_amdgcn_mfma_f32_32x32x16_bf16((A), (B), (C), 0, 0, 0)

// FINAL (R21) = R17 structure (best measured: 45.4 us) + grid 1024.
// kperm(h,i) = (i&3) + 8*(i>>2) + 4h : 32x32 D-frag row held in reg i of
// lane-group h (bijection on [0,16)). A2/A3 K-orders kperm'd at init so D regs
// pack directly into the next B operand — zero cross-lane ops.
// Dual-head L1 (heads 0,1 in one MFMA); head2 second MFMA; serialized through
// one f32x16 temp. L3 row-selective chained-C MFMA -> lanes<32 regs 0..2 hold
// (y0,y1,y2). Software-pipelined store (issued next iter). x prefetch dist 1.
// Known plateau: ~137/iter compiler marshaling insts around the 8 MFMAs
// (VALU 52% vs MFMA 25%) — not addressable from HIP source.
__global__ __launch_bounds__(256, 4) void mlp3_mfma32(
    const float* __restrict__ x,
    const float* __restrict__ W1, const float* __restrict__ b1,
    const float* __restrict__ W2, const float* __restrict__ b2,
    const float* __restrict__ W3, const float* __restrict__ b3,
    float* __restrict__ out, int n)
{
    const int tid  = (int)threadIdx.x;
    const int lane = tid & 63;
    const int row  = lane & 31;   // A-frag row / B col (point)
    const int h    = lane >> 5;   // K-half selector
    const int wv   = tid >> 6;

    // ---- weight fragments / constants (resident) ----
    bf16x8 a1d, a1s;
    {
        f32x8 t = {0.f,0.f,0.f,0.f,0.f,0.f,0.f,0.f};
        if (h == 0) {                       // heads 0,1: row = hd*16 + j
            const int hd = row >> 4, j = row & 15;
            t[0] = W1[hd * 32 + j];
            t[1] = W1[hd * 32 + 16 + j];
            t[2] = b1[hd * 16 + j];         // k=2: b1 (x K-slot 2 = 1.0)
        }
        a1d = cvt8(t);
        f32x8 s = {0.f,0.f,0.f,0.f,0.f,0.f,0.f,0.f};
        if (h == 0 && row < 16) {           // head 2 in rows 0..15
            s[0] = W1[64 + row];
            s[1] = W1[80 + row];
            s[2] = b1[32 + row];
        }
        a1s = cvt8(s);
    }
    bf16x8 a2[3], a3[3];
    f32x2  b2p[3][4];
    #pragma unroll
    for (int e = 0; e < 3; ++e) {
        f32x8 t2v = {0.f,0.f,0.f,0.f,0.f,0.f,0.f,0.f};
        if (row < 16) {
            #pragma unroll
            for (int i = 0; i < 8; ++i) {
                const int k = (i & 3) + 8 * (i >> 2) + 4 * h;   // kperm(h,i)
                t2v[i] = W2[e * 256 + k * 16 + row];
            }
        }
        a2[e] = cvt8(t2v);
        f32x8 t3 = {0.f,0.f,0.f,0.f,0.f,0.f,0.f,0.f};
        if (row == e) {
            #pragma unroll
            for (int i = 0; i < 8; ++i) {
                const int k = (i & 3) + 8 * (i >> 2) + 4 * h;
                t3[i] = W3[e * 16 + k];
            }
        }
        a3[e] = cvt8(t3);
        #pragma unroll
        for (int j = 0; j < 4; ++j) {
            const int k0 = ((2*j) & 3) + 8 * ((2*j) >> 2) + 4 * h;
            const int k1 = ((2*j+1) & 3) + 8 * ((2*j+1) >> 2) + 4 * h;
            b2p[e][j] = (f32x2){ b2[e * 16 + k0], b2[e * 16 + k1] };
        }
    }
    const float b30 = b3[0], b31 = b3[1], b32 = b3[2];
    f32x16 zz;
    #pragma unroll
    for (int r = 0; r < 16; ++r) zz[r] = 0.f;

    const int xoff = (wv * 32 + row) * 8;    // bytes into 1024B x-chunk
    const int ooff = (wv * 32 + row) * 12;   // bytes into 1536B out-chunk (lane<32)

    const int nblk   = n >> 7;               // 128 points per block-iter
    const int stride = (int)gridDim.x;
    const size_t xstep = (size_t)stride * 1024;
    const size_t ostep = (size_t)stride * 1536;

    int cb = (int)blockIdx.x;
    const char* xp = (const char*)x + (size_t)cb * 1024 + xoff;
    char*       op = (char*)out + (size_t)cb * 1536 + ooff;

    float2 xv = *reinterpret_cast<const float2*>(xp);
    float3 pend;
    char*  paddr = nullptr;
    bool   pendv = false;

    while (true) {
        const bool more = (cb + stride) < nblk;
        float2 xn;
        if (more)                             // prefetch next iter's x
            xn = *reinterpret_cast<const float2*>(xp + xstep);

        // previous iteration's store issued here: drain deadline 8 MFMAs away
        if (pendv && lane < 32)
            *reinterpret_cast<float3*>(paddr) = pend;

        // B1 k-slots {x0, x1, 1.0, 0...}
        u32x4 bu = { pkcvt((f32x2){xv.x, xv.y}), 0x3F80u, 0u, 0u };
        const bf16x8 bx = __builtin_bit_cast(bf16x8, bu);

        // ---- Layer 1, serialized through ONE temp t ----
        f32x16 t;
        u32x4 w0, w1, w2;
        t = MFMA32(a1d, bx, zz);              // heads 0,1
        #pragma unroll
        for (int j = 0; j < 4; ++j) {
            w0[j] = pkcvt(max2((f32x2){ t[2*j],     t[2*j + 1] }));
            w1[j] = pkcvt(max2((f32x2){ t[8 + 2*j], t[8 + 2*j + 1] }));
        }
        t = MFMA32(a1s, bx, zz);              // head 2 (reuses t's regs)
        #pragma unroll
        for (int j = 0; j < 4; ++j)
            w2[j] = pkcvt(max2((f32x2){ t[2*j], t[2*j + 1] }));
        const bf16x8 bh0 = __builtin_bit_cast(bf16x8, w0);
        const bf16x8 bh1 = __builtin_bit_cast(bf16x8, w1);
        const bf16x8 bh2 = __builtin_bit_cast(bf16x8, w2);

        // ---- Layers 2+3 per head; y chained in place through MFMA3's C ----
        f32x16 y;
        #pragma unroll
        for (int e = 0; e < 3; ++e) {
            const bf16x8 bh = (e == 0) ? bh0 : ((e == 1) ? bh1 : bh2);
            t = MFMA32(a2[e], bh, zz);
            u32x4 bw;
            #pragma unroll
            for (int j = 0; j < 4; ++j) {
                f32x2 q = max2((f32x2){ t[2*j], t[2*j + 1] } + b2p[e][j]);
                bw[j] = pkcvt(q);
            }
            const bf16x8 bt = __builtin_bit_cast(bf16x8, bw);
            y = MFMA32(a3[e], bt, (e == 0) ? zz : y);
        }

        pend  = make_float3(y[0] + b30, y[1] + b31, y[2] + b32);
        paddr = op;
        pendv = true;

        if (!more) break;
        cb += stride;
        xp += xstep;
        op += ostep;
        xv = xn;
    }

    if (pendv && lane < 32)
        *reinterpret_cast<float3*>(paddr) = pend;
}

extern "C" void kernel_launch(void* const* d_in, const int* in_sizes, int n_in,
                              void* d_out, int out_size, void* d_ws, size_t ws_size,
                              hipStream_t stream) {
    const float* x  = (const float*)d_in[0];
    const float* W1 = (const float*)d_in[1];
    const float* b1 = (const float*)d_in[2];
    const float* W2 = (const float*)d_in[3];
    const float* b2 = (const float*)d_in[4];
    const float* W3 = (const float*)d_in[5];
    const float* b3 = (const float*)d_in[6];
    float* out = (float*)d_out;
    (void)d_ws; (void)ws_size; (void)n_in; (void)out_size;

    const int n = in_sizes[0] / 2;   // 4194304 points (32768 * 128)
    const int block = 256;
    const int grid = 1024;           // persistent: 32 chunk-iterations per block
                                     // (halves per-block init vs 2048; 4 blocks/CU
                                     //  still > ~2.5 resident capacity)

    mlp3_mfma32<<<grid, block, 0, stream>>>(x, W1, b1, W2, b2, W3, b3, out, n);
}

// Round 22
// 45.759 us; speedup vs baseline: 1.1408x; 1.0220x over previous
//
#include <hip/hip_runtime.h>
#include <hip/hip_bf16.h>

typedef __attribute__((ext_vector_type(2)))  float f32x2;
typedef __attribute__((ext_vector_type(8)))  float f32x8;
typedef __attribute__((ext_vector_type(16))) float f32x16;
typedef __attribute__((ext_vector_type(2)))  __bf16 bf16x2;
typedef __attribute__((ext_vector_type(8)))  __bf16 bf16x8;
typedef __attribute__((ext_vector_type(4)))  unsigned int u32x4;

static __device__ __forceinline__ bf16x8 cvt8(f32x8 v) {
    return __builtin_convertvector(v, bf16x8);
}
static __device__ __forceinline__ unsigned int pkcvt(f32x2 v) {
    return __builtin_bit_cast(unsigned int, __builtin_convertvector(v, bf16x2));
}
static __device__ __forceinline__ f32x2 max2(f32x2 v) {
    const f32x2 z = {0.f, 0.f};
    return __builtin_elementwise_max(v, z);
}

#define MFMA32(A, B, C) __builtin_amdgcn_mfma_f32_32x32x16_bf16((A), (B), (C), 0, 0, 0)

// FINAL — R17 exact (best measured: 45.4 us, grid 2048).
// kperm(h,i) = (i&3) + 8*(i>>2) + 4h : 32x32 D-frag row held in reg i of
// lane-group h (bijection on [0,16)). A2/A3 K-orders kperm'd at init so D regs
// pack directly into the next B operand — zero cross-lane ops.
// Dual-head L1 (heads 0,1 in one MFMA; head2 in a second), serialized through
// one f32x16 temp. L3 row-selective chained-C MFMA -> lanes<32 regs 0..2 hold
// (y0,y1,y2). Software-pipelined store (issued next iter). x prefetch dist 1.
// Plateau analysis: MFMA 25% / VALU 52% / idle 23% at ~2.5 waves/SIMD; the
// VALU excess is compiler operand-marshaling around the MFMAs — not
// addressable from HIP source (hand-asm K-loop territory).
__global__ __launch_bounds__(256, 4) void mlp3_mfma32(
    const float* __restrict__ x,
    const float* __restrict__ W1, const float* __restrict__ b1,
    const float* __restrict__ W2, const float* __restrict__ b2,
    const float* __restrict__ W3, const float* __restrict__ b3,
    float* __restrict__ out, int n)
{
    const int tid  = (int)threadIdx.x;
    const int lane = tid & 63;
    const int row  = lane & 31;   // A-frag row / B col (point)
    const int h    = lane >> 5;   // K-half selector
    const int wv   = tid >> 6;

    // ---- weight fragments / constants (resident) ----
    bf16x8 a1d, a1s;
    {
        f32x8 t = {0.f,0.f,0.f,0.f,0.f,0.f,0.f,0.f};
        if (h == 0) {                       // heads 0,1: row = hd*16 + j
            const int hd = row >> 4, j = row & 15;
            t[0] = W1[hd * 32 + j];
            t[1] = W1[hd * 32 + 16 + j];
            t[2] = b1[hd * 16 + j];         // k=2: b1 (x K-slot 2 = 1.0)
        }
        a1d = cvt8(t);
        f32x8 s = {0.f,0.f,0.f,0.f,0.f,0.f,0.f,0.f};
        if (h == 0 && row < 16) {           // head 2 in rows 0..15
            s[0] = W1[64 + row];
            s[1] = W1[80 + row];
            s[2] = b1[32 + row];
        }
        a1s = cvt8(s);
    }
    bf16x8 a2[3], a3[3];
    f32x2  b2p[3][4];
    #pragma unroll
    for (int e = 0; e < 3; ++e) {
        f32x8 t2v = {0.f,0.f,0.f,0.f,0.f,0.f,0.f,0.f};
        if (row < 16) {
            #pragma unroll
            for (int i = 0; i < 8; ++i) {
                const int k = (i & 3) + 8 * (i >> 2) + 4 * h;   // kperm(h,i)
                t2v[i] = W2[e * 256 + k * 16 + row];
            }
        }
        a2[e] = cvt8(t2v);
        f32x8 t3 = {0.f,0.f,0.f,0.f,0.f,0.f,0.f,0.f};
        if (row == e) {
            #pragma unroll
            for (int i = 0; i < 8; ++i) {
                const int k = (i & 3) + 8 * (i >> 2) + 4 * h;
                t3[i] = W3[e * 16 + k];
            }
        }
        a3[e] = cvt8(t3);
        #pragma unroll
        for (int j = 0; j < 4; ++j) {
            const int k0 = ((2*j) & 3) + 8 * ((2*j) >> 2) + 4 * h;
            const int k1 = ((2*j+1) & 3) + 8 * ((2*j+1) >> 2) + 4 * h;
            b2p[e][j] = (f32x2){ b2[e * 16 + k0], b2[e * 16 + k1] };
        }
    }
    const float b30 = b3[0], b31 = b3[1], b32 = b3[2];
    f32x16 zz;
    #pragma unroll
    for (int r = 0; r < 16; ++r) zz[r] = 0.f;

    const int xoff = (wv * 32 + row) * 8;    // bytes into 1024B x-chunk
    const int ooff = (wv * 32 + row) * 12;   // bytes into 1536B out-chunk (lane<32)

    const int nblk   = n >> 7;               // 128 points per block-iter
    const int stride = (int)gridDim.x;
    const size_t xstep = (size_t)stride * 1024;
    const size_t ostep = (size_t)stride * 1536;

    int cb = (int)blockIdx.x;
    const char* xp = (const char*)x + (size_t)cb * 1024 + xoff;
    char*       op = (char*)out + (size_t)cb * 1536 + ooff;

    float2 xv = *reinterpret_cast<const float2*>(xp);
    float3 pend;
    char*  paddr = nullptr;
    bool   pendv = false;

    while (true) {
        const bool more = (cb + stride) < nblk;
        float2 xn;
        if (more)                             // prefetch next iter's x
            xn = *reinterpret_cast<const float2*>(xp + xstep);

        // previous iteration's store issued here: drain deadline 8 MFMAs away
        if (pendv && lane < 32)
            *reinterpret_cast<float3*>(paddr) = pend;

        // B1 k-slots {x0, x1, 1.0, 0...}
        u32x4 bu = { pkcvt((f32x2){xv.x, xv.y}), 0x3F80u, 0u, 0u };
        const bf16x8 bx = __builtin_bit_cast(bf16x8, bu);

        // ---- Layer 1, serialized through ONE temp t ----
        f32x16 t;
        u32x4 w0, w1, w2;
        t = MFMA32(a1d, bx, zz);              // heads 0,1
        #pragma unroll
        for (int j = 0; j < 4; ++j) {
            w0[j] = pkcvt(max2((f32x2){ t[2*j],     t[2*j + 1] }));
            w1[j] = pkcvt(max2((f32x2){ t[8 + 2*j], t[8 + 2*j + 1] }));
        }
        t = MFMA32(a1s, bx, zz);              // head 2 (reuses t's regs)
        #pragma unroll
        for (int j = 0; j < 4; ++j)
            w2[j] = pkcvt(max2((f32x2){ t[2*j], t[2*j + 1] }));
        const bf16x8 bh0 = __builtin_bit_cast(bf16x8, w0);
        const bf16x8 bh1 = __builtin_bit_cast(bf16x8, w1);
        const bf16x8 bh2 = __builtin_bit_cast(bf16x8, w2);

        // ---- Layers 2+3 per head; y chained in place through MFMA3's C ----
        f32x16 y;
        #pragma unroll
        for (int e = 0; e < 3; ++e) {
            const bf16x8 bh = (e == 0) ? bh0 : ((e == 1) ? bh1 : bh2);
            t = MFMA32(a2[e], bh, zz);
            u32x4 bw;
            #pragma unroll
            for (int j = 0; j < 4; ++j) {
                f32x2 q = max2((f32x2){ t[2*j], t[2*j + 1] } + b2p[e][j]);
                bw[j] = pkcvt(q);
            }
            const bf16x8 bt = __builtin_bit_cast(bf16x8, bw);
            y = MFMA32(a3[e], bt, (e == 0) ? zz : y);
        }

        pend  = make_float3(y[0] + b30, y[1] + b31, y[2] + b32);
        paddr = op;
        pendv = true;

        if (!more) break;
        cb += stride;
        xp += xstep;
        op += ostep;
        xv = xn;
    }

    if (pendv && lane < 32)
        *reinterpret_cast<float3*>(paddr) = pend;
}

extern "C" void kernel_launch(void* const* d_in, const int* in_sizes, int n_in,
                              void* d_out, int out_size, void* d_ws, size_t ws_size,
                              hipStream_t stream) {
    const float* x  = (const float*)d_in[0];
    const float* W1 = (const float*)d_in[1];
    const float* b1 = (const float*)d_in[2];
    const float* W2 = (const float*)d_in[3];
    const float* b2 = (const float*)d_in[4];
    const float* W3 = (const float*)d_in[5];
    const float* b3 = (const float*)d_in[6];
    float* out = (float*)d_out;
    (void)d_ws; (void)ws_size; (void)n_in; (void)out_size;

    const int n = in_sizes[0] / 2;   // 4194304 points (32768 * 128)
    const int block = 256;
    const int grid = 2048;           // persistent: 16 chunk-iterations per block
                                     // (R17-measured optimum; 1024 and 32768 both worse)

    mlp3_mfma32<<<grid, block, 0, stream>>>(x, W1, b1, W2, b2, W3, b3, out, n);
}

// Round 24
// 45.551 us; speedup vs baseline: 1.1460x; 1.0045x over previous
//
#include <hip/hip_runtime.h>
#include <hip/hip_bf16.h>

typedef __attribute__((ext_vector_type(2)))  float f32x2;
typedef __attribute__((ext_vector_type(8)))  float f32x8;
typedef __attribute__((ext_vector_type(16))) float f32x16;
typedef __attribute__((ext_vector_type(2)))  __bf16 bf16x2;
typedef __attribute__((ext_vector_type(8)))  __bf16 bf16x8;
typedef __attribute__((ext_vector_type(4)))  unsigned int u32x4;

static __device__ __forceinline__ bf16x8 cvt8(f32x8 v) {
    return __builtin_convertvector(v, bf16x8);
}
static __device__ __forceinline__ unsigned int pkcvt(f32x2 v) {
    return __builtin_bit_cast(unsigned int, __builtin_convertvector(v, bf16x2));
}
static __device__ __forceinline__ f32x2 max2(f32x2 v) {
    const f32x2 z = {0.f, 0.f};
    return __builtin_elementwise_max(v, z);
}

#define MFMA32(A, B, C) __builtin_amdgcn_mfma_f32_32x32x16_bf16((A), (B), (C), 0, 0, 0)

// FINAL (terminal) — R17/R22 structure, best measured 45.4-45.8 us.
// Campaign: 118 us naive VALU -> 45.4 us (2.6x). Techniques:
//  * transposed MFMA chain, col = point; D-layout -> B-layout via kperm:
//    kperm(h,i) = (i&3) + 8*(i>>2) + 4h is the 32x32 D-frag row held in reg i
//    of lane-group h (bijection on [0,16)); A2/A3 K-orders are kperm'd at
//    init so D regs 0..7 pack pairwise directly into the next B operand —
//    ZERO cross-lane ops in the hot loop.
//  * dual-head L1: heads 0,1 share one MFMA (A rows 0-15 / 16-31); b1 rides
//    in A1 k-slot 2 against B k-slot 2 = 1.0.
//  * L3 = row-selective A3 (row e carries w3_e), C chained across heads ->
//    lanes<32 end with (y0,y1,y2) in regs 0..2; epilogue is one float3 store.
//  * software-pipelined store (issued at next iter top; drain deadline sits
//    behind 8 MFMAs) — the one latency fix that measurably paid (-8%).
// Plateau: MFMA 25% / VALU 52% / idle 23% at ~2.5 waves/SIMD. The VALU excess
// (~137 insts/iter over source) is compiler operand-marshaling around MFMAs;
// constrained-asm MFMA attempt (R23) crashed (early-clobber/overlap hazard).
// Next step beyond HIP source: hand-asm K-loop with pinned register tuples.
__global__ __launch_bounds__(256, 4) void mlp3_mfma32(
    const float* __restrict__ x,
    const float* __restrict__ W1, const float* __restrict__ b1,
    const float* __restrict__ W2, const float* __restrict__ b2,
    const float* __restrict__ W3, const float* __restrict__ b3,
    float* __restrict__ out, int n)
{
    const int tid  = (int)threadIdx.x;
    const int lane = tid & 63;
    const int row  = lane & 31;   // A-frag row / B col (point)
    const int h    = lane >> 5;   // K-half selector
    const int wv   = tid >> 6;

    // ---- weight fragments / constants (resident) ----
    bf16x8 a1d, a1s;
    {
        f32x8 t = {0.f,0.f,0.f,0.f,0.f,0.f,0.f,0.f};
        if (h == 0) {                       // heads 0,1: row = hd*16 + j
            const int hd = row >> 4, j = row & 15;
            t[0] = W1[hd * 32 + j];
            t[1] = W1[hd * 32 + 16 + j];
            t[2] = b1[hd * 16 + j];         // k=2: b1 (x K-slot 2 = 1.0)
        }
        a1d = cvt8(t);
        f32x8 s = {0.f,0.f,0.f,0.f,0.f,0.f,0.f,0.f};
        if (h == 0 && row < 16) {           // head 2 in rows 0..15
            s[0] = W1[64 + row];
            s[1] = W1[80 + row];
            s[2] = b1[32 + row];
        }
        a1s = cvt8(s);
    }
    bf16x8 a2[3], a3[3];
    f32x2  b2p[3][4];
    #pragma unroll
    for (int e = 0; e < 3; ++e) {
        f32x8 t2v = {0.f,0.f,0.f,0.f,0.f,0.f,0.f,0.f};
        if (row < 16) {
            #pragma unroll
            for (int i = 0; i < 8; ++i) {
                const int k = (i & 3) + 8 * (i >> 2) + 4 * h;   // kperm(h,i)
                t2v[i] = W2[e * 256 + k * 16 + row];
            }
        }
        a2[e] = cvt8(t2v);
        f32x8 t3 = {0.f,0.f,0.f,0.f,0.f,0.f,0.f,0.f};
        if (row == e) {
            #pragma unroll
            for (int i = 0; i < 8; ++i) {
                const int k = (i & 3) + 8 * (i >> 2) + 4 * h;
                t3[i] = W3[e * 16 + k];
            }
        }
        a3[e] = cvt8(t3);
        #pragma unroll
        for (int j = 0; j < 4; ++j) {
            const int k0 = ((2*j) & 3) + 8 * ((2*j) >> 2) + 4 * h;
            const int k1 = ((2*j+1) & 3) + 8 * ((2*j+1) >> 2) + 4 * h;
            b2p[e][j] = (f32x2){ b2[e * 16 + k0], b2[e * 16 + k1] };
        }
    }
    const float b30 = b3[0], b31 = b3[1], b32 = b3[2];
    f32x16 zz;
    #pragma unroll
    for (int r = 0; r < 16; ++r) zz[r] = 0.f;

    const int xoff = (wv * 32 + row) * 8;    // bytes into 1024B x-chunk
    const int ooff = (wv * 32 + row) * 12;   // bytes into 1536B out-chunk (lane<32)

    const int nblk   = n >> 7;               // 128 points per block-iter
    const int stride = (int)gridDim.x;
    const size_t xstep = (size_t)stride * 1024;
    const size_t ostep = (size_t)stride * 1536;

    int cb = (int)blockIdx.x;
    const char* xp = (const char*)x + (size_t)cb * 1024 + xoff;
    char*       op = (char*)out + (size_t)cb * 1536 + ooff;

    float2 xv = *reinterpret_cast<const float2*>(xp);
    float3 pend;
    char*  paddr = nullptr;
    bool   pendv = false;

    while (true) {
        const bool more = (cb + stride) < nblk;
        float2 xn;
        if (more)                             // prefetch next iter's x
            xn = *reinterpret_cast<const float2*>(xp + xstep);

        // previous iteration's store issued here: drain deadline 8 MFMAs away
        if (pendv && lane < 32)
            *reinterpret_cast<float3*>(paddr) = pend;

        // B1 k-slots {x0, x1, 1.0, 0...}
        u32x4 bu = { pkcvt((f32x2){xv.x, xv.y}), 0x3F80u, 0u, 0u };
        const bf16x8 bx = __builtin_bit_cast(bf16x8, bu);

        // ---- Layer 1, serialized through ONE temp t ----
        f32x16 t;
        u32x4 w0, w1, w2;
        t = MFMA32(a1d, bx, zz);              // heads 0,1
        #pragma unroll
        for (int j = 0; j < 4; ++j) {
            w0[j] = pkcvt(max2((f32x2){ t[2*j],     t[2*j + 1] }));
            w1[j] = pkcvt(max2((f32x2){ t[8 + 2*j], t[8 + 2*j + 1] }));
        }
        t = MFMA32(a1s, bx, zz);              // head 2 (reuses t's regs)
        #pragma unroll
        for (int j = 0; j < 4; ++j)
            w2[j] = pkcvt(max2((f32x2){ t[2*j], t[2*j + 1] }));
        const bf16x8 bh0 = __builtin_bit_cast(bf16x8, w0);
        const bf16x8 bh1 = __builtin_bit_cast(bf16x8, w1);
        const bf16x8 bh2 = __builtin_bit_cast(bf16x8, w2);

        // ---- Layers 2+3 per head; y chained in place through MFMA3's C ----
        f32x16 y;
        #pragma unroll
        for (int e = 0; e < 3; ++e) {
            const bf16x8 bh = (e == 0) ? bh0 : ((e == 1) ? bh1 : bh2);
            t = MFMA32(a2[e], bh, zz);
            u32x4 bw;
            #pragma unroll
            for (int j = 0; j < 4; ++j) {
                f32x2 q = max2((f32x2){ t[2*j], t[2*j + 1] } + b2p[e][j]);
                bw[j] = pkcvt(q);
            }
            const bf16x8 bt = __builtin_bit_cast(bf16x8, bw);
            y = MFMA32(a3[e], bt, (e == 0) ? zz : y);
        }

        pend  = make_float3(y[0] + b30, y[1] + b31, y[2] + b32);
        paddr = op;
        pendv = true;

        if (!more) break;
        cb += stride;
        xp += xstep;
        op += ostep;
        xv = xn;
    }

    if (pendv && lane < 32)
        *reinterpret_cast<float3*>(paddr) = pend;
}

extern "C" void kernel_launch(void* const* d_in, const int* in_sizes, int n_in,
                              void* d_out, int out_size, void* d_ws, size_t ws_size,
                              hipStream_t stream) {
    const float* x  = (const float*)d_in[0];
    const float* W1 = (const float*)d_in[1];
    const float* b1 = (const float*)d_in[2];
    const float* W2 = (const float*)d_in[3];
    const float* b2 = (const float*)d_in[4];
    const float* W3 = (const float*)d_in[5];
    const float* b3 = (const float*)d_in[6];
    float* out = (float*)d_out;
    (void)d_ws; (void)ws_size; (void)n_in; (void)out_size;

    const int n = in_sizes[0] / 2;   // 4194304 points (32768 * 128)
    const int block = 256;
    const int grid = 2048;           // persistent: 16 chunk-iterations per block
                                     // (measured optimum; 1024 and 32768 both worse)

    mlp3_mfma32<<<grid, block, 0, stream>>>(x, W1, b1, W2, b2, W3, b3, out, n);
}